// Round 12
// baseline (780.247 us; speedup 1.0000x reference)
//
#include <hip/hip_runtime.h>
#include <stdint.h>

#define HIDDEN 4096
#define M_TOK 8192   // B*S
#define KDIM 4096

typedef __attribute__((ext_vector_type(8))) __bf16 bf16x8;
typedef __attribute__((ext_vector_type(4))) float f32x4;
typedef __attribute__((ext_vector_type(16))) float f32x16;
typedef __attribute__((ext_vector_type(8))) unsigned short u16x8;
typedef __attribute__((ext_vector_type(4))) unsigned int u32x4;

#define GAS __attribute__((address_space(1)))
#define LAS __attribute__((address_space(3)))

__device__ __forceinline__ unsigned short f2bf(float f) {
  unsigned int u = __float_as_uint(f);
  u += 0x7FFFu + ((u >> 16) & 1u);
  return (unsigned short)(u >> 16);
}
__device__ __forceinline__ float bf2f(unsigned short b) {
  return __uint_as_float(((unsigned int)b) << 16);
}

// ---------- fused fp32->bf16 conversions + bias pack, one launch ----------
__device__ __forceinline__ void cvt8(const float* __restrict__ in,
                                     unsigned short* __restrict__ out, int i) {
  const f32x4* p = (const f32x4*)in + (size_t)2 * i;
  f32x4 a = p[0], b = p[1];
  u16x8 o;
  o[0] = f2bf(a.x); o[1] = f2bf(a.y); o[2] = f2bf(a.z); o[3] = f2bf(a.w);
  o[4] = f2bf(b.x); o[5] = f2bf(b.y); o[6] = f2bf(b.z); o[7] = f2bf(b.w);
  ((u16x8*)out)[i] = o;
}

__global__ __launch_bounds__(256) void cvt_fused(
    const float* __restrict__ hs, const float* __restrict__ wq,
    const float* __restrict__ wk, const float* __restrict__ wv,
    const float* __restrict__ bq, const float* __restrict__ bk,
    const float* __restrict__ bv,
    unsigned short* __restrict__ hsb, unsigned short* __restrict__ wb,
    float* __restrict__ bias) {
  int b = blockIdx.x;
  int tid = threadIdx.x;
  if (b < 16384) {                      // hs
    cvt8(hs, hsb, b * 256 + tid);
  } else if (b < 24576) {               // wq
    cvt8(wq, wb, (b - 16384) * 256 + tid);
  } else if (b < 32768) {               // wk
    cvt8(wk, wb + 16777216, (b - 24576) * 256 + tid);
  } else if (b < 40960) {               // wv
    cvt8(wv, wb + 33554432, (b - 32768) * 256 + tid);
  } else {                              // bias pack
    int i = (b - 40960) * 256 + tid;
    float v = (i < 4096) ? bq[i] : (i < 8192) ? bk[i - 4096] : bv[i - 8192];
    bias[i] = v;
  }
}

// ============================================================================
// 256x256 QKV GEMM — R8 structure with 2 PHASES per K-tile (was 4).
// R11 analysis: at MfmaUtil 60.9 / conflicts 0 / HBM 15%, the residual ~39%
// is per-phase fixed cost (barrier arrival skew + lgkm drain, 8 pairs/K-tile).
// Keep the R8 in-window read prefetch (reads inside MFMA windows) but halve
// sync points: Pa = MM0-3 + RPB(c) in-window; Pb = MM4-7 + RPA(next).
// Stage WAR audit: Ga stage A1(!c,kt+1) -- its readers (RPB(!c), tile kt-1)
// retired at (kt-1).Pb-open LGKM0, close BAR postdates. Gb stages B0/B1/A0
// (c,kt+2) -- readers (RPA(c)) retired at Pa-open LGKM0, Pa close BAR
// postdates. VMC6 in Gb leaves exactly the 6 newest loads -> Ga's A1 + all
// older stages landed before Pb's open BAR -> Pb-window RPA(!c) race-free.
// Same 2-deep prefetch and vmcnt cadence as R8 (verified).
// ============================================================================
#define BAR() __builtin_amdgcn_s_barrier()
#define PRIO(p) __builtin_amdgcn_s_setprio(p)
#define VMC6() asm volatile("s_waitcnt vmcnt(6)" ::: "memory")
#define VMC0() asm volatile("s_waitcnt vmcnt(0)" ::: "memory")
#define LGKM0() do { asm volatile("s_waitcnt lgkmcnt(0)" ::: "memory"); \
  __builtin_amdgcn_sched_barrier(0); } while (0)
#define SB0() __builtin_amdgcn_sched_barrier(0)

__global__ __launch_bounds__(512, 2) void gemm_qkv(
    const unsigned short* __restrict__ A,   // [8192][4096] bf16
    const unsigned short* __restrict__ W,   // [12288][4096] bf16 (wq;wk;wv)
    const float* __restrict__ bias,         // [12288]
    unsigned short* __restrict__ out) {     // [3][8192][4096] bf16
  __shared__ __attribute__((aligned(16))) unsigned short lds[65536];  // 128 KiB

  int tid = threadIdx.x;
  int lane = tid & 63;
  int w = tid >> 6;
  int wm = w >> 2;        // 0..1 -> rows wm*128
  int wn = w & 3;         // 0..3 -> cols wn*64
  int l16 = lane & 15;
  int lk = lane >> 4;

  // ---- 2D XCD slab mapping (bijective; grid = 1536 = 8 XCD * 4 tm * 48 tn) ----
  int bid = blockIdx.x;
  int xcd = bid & 7;
  int local = bid >> 3;       // 0..191
  int r = local >> 5;         // 0..5 tn-round
  int i = local & 31;         // 0..31 co-resident slot
  int tm = (xcd << 2) + (i >> 3);
  int tn = (r << 3) + (i & 7);
  int m0 = tm << 8, n0 = tn << 8;

  // ---- staging source: pre-swizzled global col (3-bit XOR by row&7) ----
  int rp = tid >> 3;
  int ce = ((tid & 7) << 3) ^ ((rp & 7) << 3);
  const unsigned short* aSrc = A + (size_t)(m0 + rp) * KDIM + ce;
  const unsigned short* bSrc = W + (size_t)(n0 + rp) * KDIM + ce;
  int tid8 = tid * 8;

#define STA(b, h, kt) do { \
  __builtin_amdgcn_global_load_lds((GAS void*)(aSrc + (size_t)((h)*128) * KDIM + (kt)*64), \
      (LAS void*)(lds + (b)*16384 + (h)*8192 + tid8), 16, 0, 0); \
  __builtin_amdgcn_global_load_lds((GAS void*)(aSrc + (size_t)((h)*128 + 64) * KDIM + (kt)*64), \
      (LAS void*)(lds + (b)*16384 + (h)*8192 + 4096 + tid8), 16, 0, 0); } while (0)
#define STB(b, h, kt) do { \
  __builtin_amdgcn_global_load_lds((GAS void*)(bSrc + (size_t)((h)*128) * KDIM + (kt)*64), \
      (LAS void*)(lds + 32768 + (b)*16384 + (h)*8192 + tid8), 16, 0, 0); \
  __builtin_amdgcn_global_load_lds((GAS void*)(bSrc + (size_t)((h)*128 + 64) * KDIM + (kt)*64), \
      (LAS void*)(lds + 32768 + (b)*16384 + (h)*8192 + 4096 + tid8), 16, 0, 0); } while (0)

  // ---- fragment read addressing: R3 pattern (0 conflicts measured) ----
  int colbase = (lk << 3) ^ ((l16 & 7) << 3);
  int aRd = wm * 8192 + l16 * 64 + colbase;
  int bRd = (wn >> 1) * 8192 + (wn & 1) * 4096 + l16 * 64 + colbase;

#define RD_A(c, mi, ks) (*(const bf16x8*)(lds + (c)*16384 + (((aRd) + (mi)*1024) ^ ((ks)*32))))
#define RD_B(c, nj, ks) (*(const bf16x8*)(lds + 32768 + (c)*16384 + (((bRd) + (nj)*1024) ^ ((ks)*32))))

  bf16x8 av[8][2];
  bf16x8 bv[4][2];
  f32x4 acc[8][4] = {};

  // RPA: all B (8) + av[0-3] (8) = 16 reads. RPB: av[4-7] = 8 reads.
#define RPA(c) do { \
  bv[0][0]=RD_B(c,0,0); bv[0][1]=RD_B(c,0,1); bv[1][0]=RD_B(c,1,0); bv[1][1]=RD_B(c,1,1); \
  bv[2][0]=RD_B(c,2,0); bv[2][1]=RD_B(c,2,1); bv[3][0]=RD_B(c,3,0); bv[3][1]=RD_B(c,3,1); \
  av[0][0]=RD_A(c,0,0); av[0][1]=RD_A(c,0,1); av[1][0]=RD_A(c,1,0); av[1][1]=RD_A(c,1,1); \
  av[2][0]=RD_A(c,2,0); av[2][1]=RD_A(c,2,1); av[3][0]=RD_A(c,3,0); av[3][1]=RD_A(c,3,1); } while (0)
#define RPB(c) do { \
  av[4][0]=RD_A(c,4,0); av[4][1]=RD_A(c,4,1); av[5][0]=RD_A(c,5,0); av[5][1]=RD_A(c,5,1); \
  av[6][0]=RD_A(c,6,0); av[6][1]=RD_A(c,6,1); av[7][0]=RD_A(c,7,0); av[7][1]=RD_A(c,7,1); } while (0)

#define MFMA2(mi, nj) do { \
  acc[mi][nj] = __builtin_amdgcn_mfma_f32_16x16x32_bf16(av[mi][0], bv[nj][0], acc[mi][nj], 0, 0, 0); \
  acc[mi][nj] = __builtin_amdgcn_mfma_f32_16x16x32_bf16(av[mi][1], bv[nj][1], acc[mi][nj], 0, 0, 0); } while (0)
#define MM(mi) do { MFMA2(mi,0); MFMA2(mi,1); MFMA2(mi,2); MFMA2(mi,3); } while (0)

  // 2-phase K-tile. c = buffer; ka = kt+1 (A1 into !c); kb = kt+2 (into c).
#define KTILE2(c, ka, kb) do { \
  STA(!(c), 1, ka); \
  BAR(); LGKM0(); PRIO(1); MM(0); MM(1); MM(2); MM(3); RPB(c); PRIO(0); SB0(); BAR(); \
  STB(c, 0, kb); STB(c, 1, kb); STA(c, 0, kb); VMC6(); \
  BAR(); LGKM0(); PRIO(1); MM(4); MM(5); MM(6); MM(7); RPA(!(c)); PRIO(0); SB0(); BAR(); } while (0)

  // ---- prologue: kt0 full -> buf0, kt1 (B0,B1,A0) -> buf1; drain; prefetch ----
  STB(0, 0, 0); STB(0, 1, 0); STA(0, 0, 0); STA(0, 1, 0);
  STB(1, 0, 1); STB(1, 1, 1); STA(1, 0, 1);
  VMC0();
  BAR();
  RPA(0);

  // ---- main loop: 31 iters x 2 K-tiles (kt 0..61) ----
  for (int it = 0; it < 31; ++it) {
    int k1 = 2 * it + 1, k2 = 2 * it + 2, k3 = 2 * it + 3;
    KTILE2(0, k1, k2);
    KTILE2(1, k2, k3);
  }
  // ---- epilogue: kt62 (buf0; stage only A1 of kt63; full drain), kt63 ----
  STA(1, 1, 63);
  BAR(); LGKM0(); PRIO(1); MM(0); MM(1); MM(2); MM(3); RPB(0); PRIO(0); SB0(); BAR();
  VMC0();
  BAR(); LGKM0(); PRIO(1); MM(4); MM(5); MM(6); MM(7); RPA(1); PRIO(0); SB0(); BAR();
  BAR(); LGKM0(); PRIO(1); MM(0); MM(1); MM(2); MM(3); RPB(1); PRIO(0); SB0(); BAR();
  BAR(); LGKM0(); PRIO(1); MM(4); MM(5); MM(6); MM(7); PRIO(0);

  // ---- C write ----
  int matc = n0 >> 12;
  int ncol = (n0 & 4095) + wn * 64;
  unsigned short* O = out + (size_t)matc * M_TOK * HIDDEN;
  float bb[4];
#pragma unroll
  for (int nj = 0; nj < 4; ++nj) bb[nj] = bias[n0 + wn * 64 + nj * 16 + l16];
#pragma unroll
  for (int mi = 0; mi < 8; ++mi) {
#pragma unroll
    for (int rr = 0; rr < 4; ++rr) {
      int row = m0 + wm * 128 + mi * 16 + lk * 4 + rr;
      size_t rb = (size_t)row * HIDDEN + ncol + l16;
#pragma unroll
      for (int nj = 0; nj < 4; ++nj)
        O[rb + nj * 16] = f2bf(acc[mi][nj][rr] + bb[nj]);
    }
  }
}

// ============================================================================
// MFMA per-token attention (R11, verified: absmax 0.047): 1 wave = 1 token,
// 4 tokens/block, zero barriers.
// ============================================================================
__global__ __launch_bounds__(256) void attn_mfma(const unsigned short* __restrict__ qkv,
                                                 float* __restrict__ out) {
  __shared__ unsigned short vt[4 * 4096];   // 32 KiB: per-wave 128x32 (8 KiB)

  int tid = threadIdx.x;
  int w = tid >> 6;
  int lane = tid & 63;
  int l31 = lane & 31;
  int lg = lane >> 5;
  int m = blockIdx.x * 4 + w;

  const unsigned short* gq = qkv + (size_t)m * HIDDEN;
  const unsigned short* gk = gq + (size_t)M_TOK * HIDDEN;
  const unsigned short* gv = gk + (size_t)M_TOK * HIDDEN;
  unsigned short* vtw = vt + w * 4096;

  bf16x8 kf[8], qf[8];
#pragma unroll
  for (int kc = 0; kc < 8; ++kc) {
    kf[kc] = *(const bf16x8*)(gk + l31 * 128 + kc * 16 + lg * 8);
    qf[kc] = *(const bf16x8*)(gq + l31 * 128 + kc * 16 + lg * 8);
  }

  {
    int t = l31;
#pragma unroll
    for (int i = 0; i < 8; ++i) {
      int c0 = lg * 64 + i * 8;
      u16x8 v8 = *(const u16x8*)(gv + t * 128 + c0);
#pragma unroll
      for (int j = 0; j < 8; ++j) {
        int d = c0 + j;
        vtw[d * 32 + (((t >> 3) ^ (d & 3)) << 3) + (t & 7)] = v8[j];
      }
    }
  }

  f32x16 C = {};
#pragma unroll
  for (int kc = 0; kc < 8; ++kc)
    C = __builtin_amdgcn_mfma_f32_32x32x16_bf16(kf[kc], qf[kc], C, 0, 0, 0);

  const float scale = 0.08838834764831845f;  // 1/sqrt(128)
  float p[16];
#pragma unroll
  for (int rr = 0; rr < 16; ++rr) p[rr] = C[rr] * scale;
  float mx = p[0];
#pragma unroll
  for (int rr = 1; rr < 16; ++rr) mx = fmaxf(mx, p[rr]);
  mx = fmaxf(mx, __shfl_xor(mx, 32));
  float s = 0.f;
#pragma unroll
  for (int rr = 0; rr < 16; ++rr) { p[rr] = __expf(p[rr] - mx); s += p[rr]; }
  s += __shfl_xor(s, 32);
  float inv = 1.0f / s;
#pragma unroll
  for (int rr = 0; rr < 16; ++rr) p[rr] *= inv;

  unsigned int pk[8], op[8];
#pragma unroll
  for (int i = 0; i < 8; ++i) {
    pk[i] = (unsigned int)f2bf(p[2 * i]) | ((unsigned int)f2bf(p[2 * i + 1]) << 16);
    op[i] = (unsigned int)__shfl_xor((int)pk[i], 32);
  }
  union { u32x4 u; bf16x8 b; } A0, A1;
  A0.u = lg ? (u32x4){op[2], op[3], pk[2], pk[3]} : (u32x4){pk[0], pk[1], op[0], op[1]};
  A1.u = lg ? (u32x4){op[6], op[7], pk[6], pk[7]} : (u32x4){pk[4], pk[5], op[4], op[5]};

  asm volatile("s_waitcnt lgkmcnt(0)" ::: "memory");
  __builtin_amdgcn_sched_barrier(0);
  float* po = out + (size_t)m * HIDDEN;
#pragma unroll
  for (int dc = 0; dc < 4; ++dc) {
    int row = dc * 32 + l31;
    bf16x8 B0 = *(const bf16x8*)(vtw + row * 32 + (((0 << 1) + lg) ^ (l31 & 3)) * 8);
    bf16x8 B1 = *(const bf16x8*)(vtw + row * 32 + (((1 << 1) + lg) ^ (l31 & 3)) * 8);
    f32x16 D = {};
    D = __builtin_amdgcn_mfma_f32_32x32x16_bf16(A0.b, B0, D, 0, 0, 0);
    D = __builtin_amdgcn_mfma_f32_32x32x16_bf16(A1.b, B1, D, 0, 0, 0);
#pragma unroll
    for (int rr = 0; rr < 16; ++rr) {
      int h = (rr & 3) + 8 * (rr >> 2) + 4 * lg;
      po[h * 128 + dc * 32 + l31] = D[rr];
    }
  }
}

extern "C" void kernel_launch(void* const* d_in, const int* in_sizes, int n_in,
                              void* d_out, int out_size, void* d_ws, size_t ws_size,
                              hipStream_t stream) {
  const float* hs = (const float*)d_in[0];
  const float* wq = (const float*)d_in[1];
  const float* bq = (const float*)d_in[2];
  const float* wk = (const float*)d_in[3];
  const float* bk = (const float*)d_in[4];
  const float* wv = (const float*)d_in[5];
  const float* bv = (const float*)d_in[6];
  // wl/bl latent projection: unused by output — skipped.

  char* ws = (char*)d_ws;
  const size_t HS_OFF = 0;                    // 64 MiB
  const size_t W_OFF = 67108864;              // 96 MiB
  const size_t QKV_OFF = 167772160;           // 192 MiB
  const size_t BIAS_OFF = 369098752;          // 48 KiB
  const size_t NEED = 369147904;
  if (ws_size < NEED) return;

  unsigned short* hsb = (unsigned short*)(ws + HS_OFF);
  unsigned short* wb = (unsigned short*)(ws + W_OFF);
  unsigned short* qkv = (unsigned short*)(ws + QKV_OFF);
  float* bias = (float*)(ws + BIAS_OFF);

  cvt_fused<<<41008, 256, 0, stream>>>(hs, wq, wk, wv, bq, bk, bv, hsb, wb, bias);
  gemm_qkv<<<1536, 512, 0, stream>>>(hsb, wb, bias, qkv);   // 8 XCD x 4 tm x 48 tn
  attn_mfma<<<2048, 256, 0, stream>>>(qkv, (float*)d_out);  // 4 tokens/block
}

// Round 13
// 746.810 us; speedup vs baseline: 1.0448x; 1.0448x over previous
//
#include <hip/hip_runtime.h>
#include <stdint.h>

#define HIDDEN 4096
#define M_TOK 8192   // B*S
#define KDIM 4096

typedef __attribute__((ext_vector_type(8))) __bf16 bf16x8;
typedef __attribute__((ext_vector_type(4))) float f32x4;
typedef __attribute__((ext_vector_type(16))) float f32x16;
typedef __attribute__((ext_vector_type(8))) unsigned short u16x8;
typedef __attribute__((ext_vector_type(4))) unsigned int u32x4;

#define GAS __attribute__((address_space(1)))
#define LAS __attribute__((address_space(3)))

__device__ __forceinline__ unsigned short f2bf(float f) {
  unsigned int u = __float_as_uint(f);
  u += 0x7FFFu + ((u >> 16) & 1u);
  return (unsigned short)(u >> 16);
}
__device__ __forceinline__ float bf2f(unsigned short b) {
  return __uint_as_float(((unsigned int)b) << 16);
}

// ---------- fused fp32->bf16 conversions + bias pack, one launch ----------
__device__ __forceinline__ void cvt8(const float* __restrict__ in,
                                     unsigned short* __restrict__ out, int i) {
  const f32x4* p = (const f32x4*)in + (size_t)2 * i;
  f32x4 a = p[0], b = p[1];
  u16x8 o;
  o[0] = f2bf(a.x); o[1] = f2bf(a.y); o[2] = f2bf(a.z); o[3] = f2bf(a.w);
  o[4] = f2bf(b.x); o[5] = f2bf(b.y); o[6] = f2bf(b.z); o[7] = f2bf(b.w);
  ((u16x8*)out)[i] = o;
}

__global__ __launch_bounds__(256) void cvt_fused(
    const float* __restrict__ hs, const float* __restrict__ wq,
    const float* __restrict__ wk, const float* __restrict__ wv,
    const float* __restrict__ bq, const float* __restrict__ bk,
    const float* __restrict__ bv,
    unsigned short* __restrict__ hsb, unsigned short* __restrict__ wb,
    float* __restrict__ bias) {
  int b = blockIdx.x;
  int tid = threadIdx.x;
  if (b < 16384) {                      // hs
    cvt8(hs, hsb, b * 256 + tid);
  } else if (b < 24576) {               // wq
    cvt8(wq, wb, (b - 16384) * 256 + tid);
  } else if (b < 32768) {               // wk
    cvt8(wk, wb + 16777216, (b - 24576) * 256 + tid);
  } else if (b < 40960) {               // wv
    cvt8(wv, wb + 33554432, (b - 32768) * 256 + tid);
  } else {                              // bias pack
    int i = (b - 40960) * 256 + tid;
    float v = (i < 4096) ? bq[i] : (i < 8192) ? bk[i - 4096] : bv[i - 8192];
    bias[i] = v;
  }
}

// ============================================================================
// 256x256 QKV GEMM — R8 config (session best: MfmaUtil 60.9, conflicts 0,
// FETCH 0.59e6, ~660-685us). R12 post-mortem: 2-phase merge regressed (54%
// MfmaUtil) — 16-read bursts no longer hide under the MFMA window and the
// 6-gload stage burst contends on the LDS write port. Phase granularity of
// this 4-phase in-window-prefetch schedule is the measured optimum: finer
// (R7) and coarser (R12) both lose. Rejected structures this session:
// 32x32 MFMA (R4, bank conflicts), 128^2 (R6, FLOP/LDS-byte ratio), BK=32
// (R9, conflicts+regs), 128x192 (R10, FETCH blowup).
// ============================================================================
#define BAR() __builtin_amdgcn_s_barrier()
#define PRIO(p) __builtin_amdgcn_s_setprio(p)
#define VMC6() asm volatile("s_waitcnt vmcnt(6)" ::: "memory")
#define VMC0() asm volatile("s_waitcnt vmcnt(0)" ::: "memory")
#define LGKM0() do { asm volatile("s_waitcnt lgkmcnt(0)" ::: "memory"); \
  __builtin_amdgcn_sched_barrier(0); } while (0)
#define SB0() __builtin_amdgcn_sched_barrier(0)

__global__ __launch_bounds__(512, 2) void gemm_qkv(
    const unsigned short* __restrict__ A,   // [8192][4096] bf16
    const unsigned short* __restrict__ W,   // [12288][4096] bf16 (wq;wk;wv)
    const float* __restrict__ bias,         // [12288]
    unsigned short* __restrict__ out) {     // [3][8192][4096] bf16
  __shared__ __attribute__((aligned(16))) unsigned short lds[65536];  // 128 KiB

  int tid = threadIdx.x;
  int lane = tid & 63;
  int w = tid >> 6;
  int wm = w >> 2;        // 0..1 -> rows wm*128
  int wn = w & 3;         // 0..3 -> cols wn*64
  int l16 = lane & 15;
  int lk = lane >> 4;

  // ---- 2D XCD slab mapping (bijective; grid = 1536 = 8 XCD * 4 tm * 48 tn) ----
  int bid = blockIdx.x;
  int xcd = bid & 7;
  int local = bid >> 3;       // 0..191
  int r = local >> 5;         // 0..5 tn-round
  int i = local & 31;         // 0..31 co-resident slot
  int tm = (xcd << 2) + (i >> 3);
  int tn = (r << 3) + (i & 7);
  int m0 = tm << 8, n0 = tn << 8;

  // ---- staging source: pre-swizzled global col (3-bit XOR by row&7) ----
  int rp = tid >> 3;
  int ce = ((tid & 7) << 3) ^ ((rp & 7) << 3);
  const unsigned short* aSrc = A + (size_t)(m0 + rp) * KDIM + ce;
  const unsigned short* bSrc = W + (size_t)(n0 + rp) * KDIM + ce;
  int tid8 = tid * 8;

#define STA(b, h, kt) do { \
  __builtin_amdgcn_global_load_lds((GAS void*)(aSrc + (size_t)((h)*128) * KDIM + (kt)*64), \
      (LAS void*)(lds + (b)*16384 + (h)*8192 + tid8), 16, 0, 0); \
  __builtin_amdgcn_global_load_lds((GAS void*)(aSrc + (size_t)((h)*128 + 64) * KDIM + (kt)*64), \
      (LAS void*)(lds + (b)*16384 + (h)*8192 + 4096 + tid8), 16, 0, 0); } while (0)
#define STB(b, h, kt) do { \
  __builtin_amdgcn_global_load_lds((GAS void*)(bSrc + (size_t)((h)*128) * KDIM + (kt)*64), \
      (LAS void*)(lds + 32768 + (b)*16384 + (h)*8192 + tid8), 16, 0, 0); \
  __builtin_amdgcn_global_load_lds((GAS void*)(bSrc + (size_t)((h)*128 + 64) * KDIM + (kt)*64), \
      (LAS void*)(lds + 32768 + (b)*16384 + (h)*8192 + 4096 + tid8), 16, 0, 0); } while (0)

  // ---- fragment read addressing: R3 pattern (0 conflicts measured) ----
  int colbase = (lk << 3) ^ ((l16 & 7) << 3);
  int aRd = wm * 8192 + l16 * 64 + colbase;
  int bRd = (wn >> 1) * 8192 + (wn & 1) * 4096 + l16 * 64 + colbase;

#define RD_A(c, mi, ks) (*(const bf16x8*)(lds + (c)*16384 + (((aRd) + (mi)*1024) ^ ((ks)*32))))
#define RD_B(c, nj, ks) (*(const bf16x8*)(lds + 32768 + (c)*16384 + (((bRd) + (nj)*1024) ^ ((ks)*32))))

  bf16x8 av[8][2];
  bf16x8 bv[4][2];
  f32x4 acc[8][4] = {};

#define RP1(c) do { \
  bv[0][0]=RD_B(c,0,0); bv[0][1]=RD_B(c,0,1); bv[1][0]=RD_B(c,1,0); bv[1][1]=RD_B(c,1,1); \
  bv[2][0]=RD_B(c,2,0); bv[2][1]=RD_B(c,2,1); bv[3][0]=RD_B(c,3,0); bv[3][1]=RD_B(c,3,1); \
  av[0][0]=RD_A(c,0,0); av[0][1]=RD_A(c,0,1); av[1][0]=RD_A(c,1,0); av[1][1]=RD_A(c,1,1); } while (0)
#define RP2(c) do { \
  av[2][0]=RD_A(c,2,0); av[2][1]=RD_A(c,2,1); av[3][0]=RD_A(c,3,0); av[3][1]=RD_A(c,3,1); \
  av[4][0]=RD_A(c,4,0); av[4][1]=RD_A(c,4,1); av[5][0]=RD_A(c,5,0); av[5][1]=RD_A(c,5,1); } while (0)
#define RP3(c) do { \
  av[6][0]=RD_A(c,6,0); av[6][1]=RD_A(c,6,1); av[7][0]=RD_A(c,7,0); av[7][1]=RD_A(c,7,1); } while (0)

#define MFMA2(mi, nj) do { \
  acc[mi][nj] = __builtin_amdgcn_mfma_f32_16x16x32_bf16(av[mi][0], bv[nj][0], acc[mi][nj], 0, 0, 0); \
  acc[mi][nj] = __builtin_amdgcn_mfma_f32_16x16x32_bf16(av[mi][1], bv[nj][1], acc[mi][nj], 0, 0, 0); } while (0)
#define MM(mi) do { MFMA2(mi,0); MFMA2(mi,1); MFMA2(mi,2); MFMA2(mi,3); } while (0)

#define KTILE(c, ka, kb) do { \
  STA(!(c), 1, ka); \
  BAR(); LGKM0(); PRIO(1); MM(0); MM(1); RP2(c); PRIO(0); SB0(); BAR(); \
  STB(c, 0, kb); \
  BAR(); LGKM0(); PRIO(1); MM(2); MM(3); RP3(c); PRIO(0); SB0(); BAR(); \
  STB(c, 1, kb); \
  BAR(); LGKM0(); PRIO(1); MM(4); MM(5); PRIO(0); SB0(); BAR(); \
  STA(c, 0, kb); VMC6(); \
  BAR(); SB0(); PRIO(1); MM(6); MM(7); RP1(!(c)); PRIO(0); SB0(); BAR(); } while (0)

  // ---- prologue ----
  STB(0, 0, 0); STB(0, 1, 0); STA(0, 0, 0); STA(0, 1, 0);
  STB(1, 0, 1); STB(1, 1, 1); STA(1, 0, 1);
  VMC0();
  BAR();
  RP1(0);

  for (int it = 0; it < 31; ++it) {
    int k1 = 2 * it + 1, k2 = 2 * it + 2, k3 = 2 * it + 3;
    KTILE(0, k1, k2);
    KTILE(1, k2, k3);
  }
  // ---- epilogue: kt62 (buf0; stage only A1 of kt63; full drain), kt63 ----
  STA(1, 1, 63);
  BAR(); LGKM0(); PRIO(1); MM(0); MM(1); RP2(0); PRIO(0); SB0(); BAR();
  BAR(); LGKM0(); PRIO(1); MM(2); MM(3); RP3(0); PRIO(0); SB0(); BAR();
  BAR(); LGKM0(); PRIO(1); MM(4); MM(5); PRIO(0); SB0(); BAR();
  VMC0();
  BAR(); SB0(); PRIO(1); MM(6); MM(7); RP1(1); PRIO(0); SB0(); BAR();
  BAR(); LGKM0(); PRIO(1); MM(0); MM(1); RP2(1); PRIO(0); SB0(); BAR();
  BAR(); LGKM0(); PRIO(1); MM(2); MM(3); RP3(1); PRIO(0); SB0(); BAR();
  BAR(); LGKM0(); PRIO(1); MM(4); MM(5); PRIO(0); SB0(); BAR();
  BAR(); LGKM0(); PRIO(1); MM(6); MM(7); PRIO(0);

  // ---- C write ----
  int matc = n0 >> 12;
  int ncol = (n0 & 4095) + wn * 64;
  unsigned short* O = out + (size_t)matc * M_TOK * HIDDEN;
  float bb[4];
#pragma unroll
  for (int nj = 0; nj < 4; ++nj) bb[nj] = bias[n0 + wn * 64 + nj * 16 + l16];
#pragma unroll
  for (int mi = 0; mi < 8; ++mi) {
#pragma unroll
    for (int rr = 0; rr < 4; ++rr) {
      int row = m0 + wm * 128 + mi * 16 + lk * 4 + rr;
      size_t rb = (size_t)row * HIDDEN + ncol + l16;
#pragma unroll
      for (int nj = 0; nj < 4; ++nj)
        O[rb + nj * 16] = f2bf(acc[mi][nj][rr] + bb[nj]);
    }
  }
}

// ============================================================================
// MFMA per-token attention (R11, verified: absmax 0.047): 1 wave = 1 token,
// 4 tokens/block, zero barriers.
// ============================================================================
__global__ __launch_bounds__(256) void attn_mfma(const unsigned short* __restrict__ qkv,
                                                 float* __restrict__ out) {
  __shared__ unsigned short vt[4 * 4096];   // 32 KiB: per-wave 128x32 (8 KiB)

  int tid = threadIdx.x;
  int w = tid >> 6;
  int lane = tid & 63;
  int l31 = lane & 31;
  int lg = lane >> 5;
  int m = blockIdx.x * 4 + w;

  const unsigned short* gq = qkv + (size_t)m * HIDDEN;
  const unsigned short* gk = gq + (size_t)M_TOK * HIDDEN;
  const unsigned short* gv = gk + (size_t)M_TOK * HIDDEN;
  unsigned short* vtw = vt + w * 4096;

  bf16x8 kf[8], qf[8];
#pragma unroll
  for (int kc = 0; kc < 8; ++kc) {
    kf[kc] = *(const bf16x8*)(gk + l31 * 128 + kc * 16 + lg * 8);
    qf[kc] = *(const bf16x8*)(gq + l31 * 128 + kc * 16 + lg * 8);
  }

  {
    int t = l31;
#pragma unroll
    for (int i = 0; i < 8; ++i) {
      int c0 = lg * 64 + i * 8;
      u16x8 v8 = *(const u16x8*)(gv + t * 128 + c0);
#pragma unroll
      for (int j = 0; j < 8; ++j) {
        int d = c0 + j;
        vtw[d * 32 + (((t >> 3) ^ (d & 3)) << 3) + (t & 7)] = v8[j];
      }
    }
  }

  f32x16 C = {};
#pragma unroll
  for (int kc = 0; kc < 8; ++kc)
    C = __builtin_amdgcn_mfma_f32_32x32x16_bf16(kf[kc], qf[kc], C, 0, 0, 0);

  const float scale = 0.08838834764831845f;  // 1/sqrt(128)
  float p[16];
#pragma unroll
  for (int rr = 0; rr < 16; ++rr) p[rr] = C[rr] * scale;
  float mx = p[0];
#pragma unroll
  for (int rr = 1; rr < 16; ++rr) mx = fmaxf(mx, p[rr]);
  mx = fmaxf(mx, __shfl_xor(mx, 32));
  float s = 0.f;
#pragma unroll
  for (int rr = 0; rr < 16; ++rr) { p[rr] = __expf(p[rr] - mx); s += p[rr]; }
  s += __shfl_xor(s, 32);
  float inv = 1.0f / s;
#pragma unroll
  for (int rr = 0; rr < 16; ++rr) p[rr] *= inv;

  unsigned int pk[8], op[8];
#pragma unroll
  for (int i = 0; i < 8; ++i) {
    pk[i] = (unsigned int)f2bf(p[2 * i]) | ((unsigned int)f2bf(p[2 * i + 1]) << 16);
    op[i] = (unsigned int)__shfl_xor((int)pk[i], 32);
  }
  union { u32x4 u; bf16x8 b; } A0, A1;
  A0.u = lg ? (u32x4){op[2], op[3], pk[2], pk[3]} : (u32x4){pk[0], pk[1], op[0], op[1]};
  A1.u = lg ? (u32x4){op[6], op[7], pk[6], pk[7]} : (u32x4){pk[4], pk[5], op[4], op[5]};

  asm volatile("s_waitcnt lgkmcnt(0)" ::: "memory");
  __builtin_amdgcn_sched_barrier(0);
  float* po = out + (size_t)m * HIDDEN;
#pragma unroll
  for (int dc = 0; dc < 4; ++dc) {
    int row = dc * 32 + l31;
    bf16x8 B0 = *(const bf16x8*)(vtw + row * 32 + (((0 << 1) + lg) ^ (l31 & 3)) * 8);
    bf16x8 B1 = *(const bf16x8*)(vtw + row * 32 + (((1 << 1) + lg) ^ (l31 & 3)) * 8);
    f32x16 D = {};
    D = __builtin_amdgcn_mfma_f32_32x32x16_bf16(A0.b, B0, D, 0, 0, 0);
    D = __builtin_amdgcn_mfma_f32_32x32x16_bf16(A1.b, B1, D, 0, 0, 0);
#pragma unroll
    for (int rr = 0; rr < 16; ++rr) {
      int h = (rr & 3) + 8 * (rr >> 2) + 4 * lg;
      po[h * 128 + dc * 32 + l31] = D[rr];
    }
  }
}

extern "C" void kernel_launch(void* const* d_in, const int* in_sizes, int n_in,
                              void* d_out, int out_size, void* d_ws, size_t ws_size,
                              hipStream_t stream) {
  const float* hs = (const float*)d_in[0];
  const float* wq = (const float*)d_in[1];
  const float* bq = (const float*)d_in[2];
  const float* wk = (const float*)d_in[3];
  const float* bk = (const float*)d_in[4];
  const float* wv = (const float*)d_in[5];
  const float* bv = (const float*)d_in[6];
  // wl/bl latent projection: unused by output — skipped.

  char* ws = (char*)d_ws;
  const size_t HS_OFF = 0;                    // 64 MiB
  const size_t W_OFF = 67108864;              // 96 MiB
  const size_t QKV_OFF = 167772160;           // 192 MiB
  const size_t BIAS_OFF = 369098752;          // 48 KiB
  const size_t NEED = 369147904;
  if (ws_size < NEED) return;

  unsigned short* hsb = (unsigned short*)(ws + HS_OFF);
  unsigned short* wb = (unsigned short*)(ws + W_OFF);
  unsigned short* qkv = (unsigned short*)(ws + QKV_OFF);
  float* bias = (float*)(ws + BIAS_OFF);

  cvt_fused<<<41008, 256, 0, stream>>>(hs, wq, wk, wv, bq, bk, bv, hsb, wb, bias);
  gemm_qkv<<<1536, 512, 0, stream>>>(hsb, wb, bias, qkv);   // 8 XCD x 4 tm x 48 tn
  attn_mfma<<<2048, 256, 0, stream>>>(qkv, (float*)d_out);  // 4 tokens/block
}